// Round 2
// baseline (27.584 us; speedup 1.0000x reference)
//
#include <hip/hip_runtime.h>

// UserEmbedding: out[b, d] = W[d, x[b]]
//   x: [16384] int32, W: [64, 1_000_000] f32 row-major, out: [16384, 64] f32
//
// Scatter-gather is latency/MLP-bound, not bytes-bound (67 MB of lines vs
// 26 us measured = 2.6 TB/s). K=8 outputs per thread -> 8 independent
// x-loads then 8 independent scattered W-loads in flight per thread,
// raising per-wave outstanding transactions 64 -> 512.
//
// Element mapping: e_k = base + k*(TOTAL/K), base = blockIdx*256+tid.
// TOTAL/K = 131072 is a multiple of 64, so d = base & 63 is k-invariant and
// stores stay fully coalesced (256 B per wave per k).

#define NUM_USERS 1000000
#define DIM 64
#define BATCH 16384
#define TOTAL (BATCH * DIM)   // 1,048,576
#define K 8
#define NTHREADS (TOTAL / K)  // 131,072
#define KSTRIDE (TOTAL / K)   // elements between a thread's outputs
#define BSTRIDE (KSTRIDE / DIM) // 2048 batch rows between a thread's outputs

__global__ __launch_bounds__(256) void UserEmbedding_61873298866785_kernel(
    const int* __restrict__ x,
    const float* __restrict__ W,
    float* __restrict__ out) {
    const int base = blockIdx.x * 256 + threadIdx.x;  // 0 .. NTHREADS-1
    const int b0 = base >> 6;          // wave-uniform batch row
    const int d  = base & 63;          // lane id = embedding dim
    const float* Wd = W + (size_t)d * NUM_USERS;

    int u[K];
#pragma unroll
    for (int k = 0; k < K; ++k) u[k] = x[b0 + k * BSTRIDE];   // broadcast loads

    float v[K];
#pragma unroll
    for (int k = 0; k < K; ++k) v[k] = Wd[u[k]];              // scattered loads

#pragma unroll
    for (int k = 0; k < K; ++k) out[base + k * KSTRIDE] = v[k];  // coalesced
}

extern "C" void kernel_launch(void* const* d_in, const int* in_sizes, int n_in,
                              void* d_out, int out_size, void* d_ws, size_t ws_size,
                              hipStream_t stream) {
    const int* x = (const int*)d_in[0];
    const float* W = (const float*)d_in[1];
    float* out = (float*)d_out;

    const int block = 256;
    const int grid = NTHREADS / block;  // 512
    UserEmbedding_61873298866785_kernel<<<grid, block, 0, stream>>>(x, W, out);
}